// Round 22
// baseline (75.750 us; speedup 1.0000x reference)
//
#include <hip/hip_runtime.h>
#include <math.h>

// SSIM loss, round 22 = r16 with BARRIER-FREE wave-private staging (r14's
// theory, redone without its confounds: S-buffer is gone since r15, so LDS =
// 4 waves x {x,y} x 48x40 f16 = 30.7 KB -> 5 blocks/CU, not r14's 2).
//  - each wave stages its own 48x32 panel (12 coalesced float4 loads/lane,
//    16-col halo overlap with neighbor waves served by L1/L2).
//  - panel pitch 40 f16 (80 B): fragment ds_read_b128 16B-aligned, <=2-way.
//  - NO __syncthreads between staging and compute (wave reads only its own
//    panel; DS ordering within a wave via lgkmcnt). Only barrier: final
//    4-word reduction.
// Phase A/C byte-identical to validated r16: constexpr band tables, K=32
// band MFMA h-blur, packed C in regs, in-wave bpermute transpose, K=32 MFMA
// v-blur, register epilogue, XCD swizzle, 2-dispatch deterministic reduce.

typedef _Float16 f16x8 __attribute__((ext_vector_type(8)));
typedef _Float16 f16x4 __attribute__((ext_vector_type(4)));
typedef float f32x4 __attribute__((ext_vector_type(4)));
typedef _Float16 h2 __attribute__((ext_vector_type(2)));

#define PNP 40                   // f16 pitch of panel rows (32 data + 8 pad)
#define NPIX (16 * 3 * 512 * 512)
#define NBLOCKS (48 * 16 * 8)    // 6144; % 8 == 0 -> bijective XCD swizzle

union U4 { f16x4 v; h2 p[2]; };
union U8 { f16x8 v; h2 p[4]; };
union UB { unsigned u[4]; f16x8 v; };
union UP { h2 h; unsigned u; };

static __device__ __forceinline__ h2 pkrtz(float a, float b) {
    auto r = __builtin_amdgcn_cvt_pkrtz(a, b);
    union { decltype(r) f; h2 h; } x; x.f = r; return x.h;
}
static __device__ __forceinline__ unsigned pk_u32(float a, float b) {
    UP x; x.h = pkrtz(a, b); return x.u;
}

// ---- compile-time band-fragment tables (validated r16) -----------------
struct alignas(16) BandTabs { float bh[64][8]; float wv[64][8]; };
static constexpr BandTabs mk_tabs() {
    constexpr float GW[11] = {
        0.00102838f, 0.00759876f, 0.03600026f, 0.10936083f, 0.21300567f,
        0.26601190f, 0.21300567f, 0.10936083f, 0.03600026f, 0.00759876f,
        0.00102838f};
    BandTabs t{};
    for (int lane = 0; lane < 64; ++lane) {
        const int l15 = lane & 15, kg = lane >> 4;
        for (int j = 0; j < 8; ++j) {
            const int kk = kg * 8 + j;
            const int ib = kk - l15 - 3;
            const int iv = kk - l15;
            t.bh[lane][j] = (ib >= 0 && ib < 11) ? GW[ib] : 0.0f;
            t.wv[lane][j] = (iv >= 0 && iv < 11) ? GW[iv] : 0.0f;
        }
    }
    return t;
}
__device__ constexpr BandTabs TAB = mk_tabs();

static __device__ __forceinline__ f16x8 load_band(const float* row) {
    const float4 a = *(const float4*)row;
    const float4 b = *(const float4*)(row + 4);
    U8 r;
    r.p[0] = pkrtz(a.x, a.y); r.p[1] = pkrtz(a.z, a.w);
    r.p[2] = pkrtz(b.x, b.y); r.p[3] = pkrtz(b.z, b.w);
    return r.v;
}

__global__ __launch_bounds__(256, 5) void ssim_main(
    const float* __restrict__ X, const float* __restrict__ Y,
    float* __restrict__ partial)
{
    __shared__ _Float16 panel[4][2][48 * PNP];   // 30,720 B
    __shared__ float red[4];

    const int tid = threadIdx.x;
    const int bid = blockIdx.x;

    // bijective XCD swizzle
    const int wg    = (bid & 7) * (NBLOCKS / 8) + (bid >> 3);
    const int plane = wg >> 7;           // 128 tiles per plane
    const int tt    = wg & 127;
    const int tr    = tt >> 3;           // 0..15 (row tiles, 32 rows)
    const int tc    = tt & 7;            // 0..7  (col tiles, 64 cols)

    const float* xp = X + (size_t)plane * (512 * 512);
    const float* yp = Y + (size_t)plane * (512 * 512);
    const int row0 = tr * 32 - 5;        // global row of panel row 0
    const int colT = tc * 64;            // global col of output col 0

    const int w    = tid >> 6;           // wave id = n-tile (out cols 16w..)
    const int lane = tid & 63;
    const int l15  = lane & 15;
    const int kg   = lane >> 4;

    // ---- wave-private staging: 48 rows x 32 cols (12 coalesced float4) ----
    const int lr = lane >> 3;            // row-in-group 0..7
    const int q8 = lane & 7;             // col quad 0..7
    const int gcol = colT + 16 * w - 8 + 4 * q8;   // per-lane constant
    const bool colOK = (gcol >= 0) && (gcol <= 508);

    const float4 f4z = make_float4(0.f, 0.f, 0.f, 0.f);
    float4 px[6], py[6];
#pragma unroll
    for (int li = 0; li < 6; ++li) {
        const int gr = row0 + 8 * li + lr;
        const bool ok = colOK && ((unsigned)gr < 512u);
        px[li] = ok ? *(const float4*)(xp + gr * 512 + gcol) : f4z;
        py[li] = ok ? *(const float4*)(yp + gr * 512 + gcol) : f4z;
    }

    _Float16* pnx = panel[w][0];
    _Float16* pny = panel[w][1];
#pragma unroll
    for (int li = 0; li < 6; ++li) {
        const int off = (8 * li + lr) * PNP + 4 * q8;
        U4 tx, ty;
        tx.p[0] = pkrtz(px[li].x, px[li].y); tx.p[1] = pkrtz(px[li].z, px[li].w);
        ty.p[0] = pkrtz(py[li].x, py[li].y); ty.p[1] = pkrtz(py[li].z, py[li].w);
        *(f16x4*)(pnx + off) = tx.v;
        *(f16x4*)(pny + off) = ty.v;
    }
    // no __syncthreads: this wave reads only its own panel (lgkmcnt orders)

    // band fragments from constant tables
    const f16x8 BH = load_band(TAB.bh[lane]);
    const f16x8 WV = load_band(TAB.wv[lane]);

    const f32x4 zero4 = {0.f, 0.f, 0.f, 0.f};

    // ---- Phase A: fragments, products, h-blur MFMA -> packed C in regs ----
    // A k=0 <-> panel col 0; lane reads 8 f16 at panel[mt*16+l15][8kg]
    // (byte offset row*80 + kg*16: 16B-aligned ds_read_b128).
    unsigned pq[4][3][2];
#pragma unroll
    for (int mt = 0; mt < 3; ++mt) {
        const int r = mt * 16 + l15;
        const f16x8 fx = *(const f16x8*)(pnx + r * PNP + 8 * kg);
        const f16x8 fy = *(const f16x8*)(pny + r * PNP + 8 * kg);
        const f16x8 fxy = fx * fy;
        const f16x8 fss = fx * fx + fy * fy;

        const f32x4 c0 = __builtin_amdgcn_mfma_f32_16x16x32_f16(fx,  BH, zero4, 0, 0, 0);
        const f32x4 c1 = __builtin_amdgcn_mfma_f32_16x16x32_f16(fy,  BH, zero4, 0, 0, 0);
        const f32x4 c2 = __builtin_amdgcn_mfma_f32_16x16x32_f16(fss, BH, zero4, 0, 0, 0);
        const f32x4 c3 = __builtin_amdgcn_mfma_f32_16x16x32_f16(fxy, BH, zero4, 0, 0, 0);

        pq[0][mt][0] = pk_u32(c0[0], c0[1]); pq[0][mt][1] = pk_u32(c0[2], c0[3]);
        pq[1][mt][0] = pk_u32(c1[0], c1[1]); pq[1][mt][1] = pk_u32(c1[2], c1[3]);
        pq[2][mt][0] = pk_u32(c2[0], c2[1]); pq[2][mt][1] = pk_u32(c2[2], c2[3]);
        pq[3][mt][0] = pk_u32(c3[0], c3[1]); pq[3][mt][1] = pk_u32(c3[2], c3[3]);
    }

    // ---- Phase C: bpermute-built B-frags, v-blur MFMA, epilogue ----
    const int addrA = ((2 * (kg & 1)) * 16 + l15) * 4;   // byte lane addr
    const int addrB = addrA + 64;                        // +16 lanes
    const bool hi = (kg >= 2);                           // mt-set = mtv+1

    const float C1 = 0.0004f, C2 = 0.0036f;
    float lsum = 0.f;
#pragma unroll
    for (int mtv = 0; mtv < 2; ++mtv) {
        f32x4 v[4];
#pragma unroll
        for (int q = 0; q < 4; ++q) {
            const unsigned s0 = hi ? pq[q][mtv + 1][0] : pq[q][mtv][0];
            const unsigned s1 = hi ? pq[q][mtv + 1][1] : pq[q][mtv][1];
            UB b;
            b.u[0] = (unsigned)__builtin_amdgcn_ds_bpermute(addrA, (int)s0);
            b.u[1] = (unsigned)__builtin_amdgcn_ds_bpermute(addrA, (int)s1);
            b.u[2] = (unsigned)__builtin_amdgcn_ds_bpermute(addrB, (int)s0);
            b.u[3] = (unsigned)__builtin_amdgcn_ds_bpermute(addrB, (int)s1);
            v[q] = __builtin_amdgcn_mfma_f32_16x16x32_f16(WV, b.v, zero4, 0, 0, 0);
        }
#pragma unroll
        for (int r2 = 0; r2 < 4; ++r2) {
            const float mux = v[0][r2], muy = v[1][r2];
            const float ess = v[2][r2], exy = v[3][r2];
            const float mux2 = mux * mux, muy2 = muy * muy, muxy = mux * muy;
            const float svar = fmaxf(ess - mux2 - muy2, 0.f);  // sxx+syy
            const float sxy = exy - muxy;
            const float num = (2.f * muxy + C1) * (2.f * sxy + C2);
            const float den = (mux2 + muy2 + C1) * (svar + C2);
            lsum += num * __builtin_amdgcn_rcpf(den);
        }
    }

    // ---- only block barrier: 4-word reduction ----
#pragma unroll
    for (int off = 32; off > 0; off >>= 1)
        lsum += __shfl_down(lsum, off, 64);
    if (lane == 0) red[w] = lsum;
    __syncthreads();
    if (tid == 0)
        partial[bid] = red[0] + red[1] + red[2] + red[3];
}

__global__ void ssim_final(const float* __restrict__ partial,
                           float* __restrict__ out)
{
    const int tid = threadIdx.x;
    double s = 0.0;
    for (int i = tid; i < NBLOCKS; i += 1024) s += (double)partial[i];
#pragma unroll
    for (int off = 32; off > 0; off >>= 1)
        s += __shfl_down(s, off, 64);
    __shared__ double ws[16];
    if ((tid & 63) == 0) ws[tid >> 6] = s;
    __syncthreads();
    if (tid == 0) {
        double tot = 0.0;
#pragma unroll
        for (int i = 0; i < 16; ++i) tot += ws[i];
        out[0] = (float)(1.0 - tot / (double)NPIX);
    }
}

extern "C" void kernel_launch(void* const* d_in, const int* in_sizes, int n_in,
                              void* d_out, int out_size, void* d_ws, size_t ws_size,
                              hipStream_t stream)
{
    const float* x = (const float*)d_in[0];   // pred
    const float* y = (const float*)d_in[1];   // target
    float* partial = (float*)d_ws;            // NBLOCKS*4 = 24,576 B
    float* out = (float*)d_out;

    ssim_main<<<NBLOCKS, 256, 0, stream>>>(x, y, partial);
    ssim_final<<<1, 1024, 0, stream>>>(partial, out);
}

// Round 23
// 31.973 us; speedup vs baseline: 2.3692x; 2.3692x over previous
//
#include <hip/hip_runtime.h>
#include <math.h>

// SSIM loss, FINAL (= r16/r21, best measured: 32.06 us bench, 5.5x over the
// r1 baseline). Structure: coalesced f32->f16 LDS staging (17.4 KB),
// constexpr band-fragment tables, K=32 band MFMA h-blur, in-wave bpermute
// transpose (no S buffer, 1 barrier), K=32 MFMA v-blur, 4-quantity algebra
// (blur(x),blur(y),blur(x^2+y^2),blur(xy)), register SSIM epilogue,
// bijective XCD swizzle, deterministic 2-dispatch reduction.
// Tested-null at this floor: occupancy 26-67%, -41% DS, -bpermute, -17% work.
// Tested-regress: intra-block prefetch, persistent pipeline, fused finish,
// barrier-free wave-private staging (x2). See session journal r1-r22.

typedef _Float16 f16x8 __attribute__((ext_vector_type(8)));
typedef _Float16 f16x4 __attribute__((ext_vector_type(4)));
typedef float f32x4 __attribute__((ext_vector_type(4)));
typedef _Float16 h2 __attribute__((ext_vector_type(2)));

#define RAWP 88                  // f16 pitch of raw rows (80 data + 8 pad)
#define NPIX (16 * 3 * 512 * 512)
#define NBLOCKS (48 * 16 * 8)    // 6144; % 8 == 0 -> bijective XCD swizzle

union U4 { f16x4 v; h2 p[2]; };
union U8 { f16x8 v; h2 p[4]; };
union UB { unsigned u[4]; f16x8 v; };
union UP { h2 h; unsigned u; };

static __device__ __forceinline__ h2 pkrtz(float a, float b) {
    auto r = __builtin_amdgcn_cvt_pkrtz(a, b);
    union { decltype(r) f; h2 h; } x; x.f = r; return x.h;
}
static __device__ __forceinline__ unsigned pk_u32(float a, float b) {
    UP x; x.h = pkrtz(a, b); return x.u;
}

// ---- compile-time band-fragment tables --------------------------------
// BH[k][n] = w[k-n-3] at lane(l15=n, kg), k = 8kg+j.
// WV[m][k] = w[k-m]   at lane(l15=m, kg), k = 8kg+j.
struct alignas(16) BandTabs { float bh[64][8]; float wv[64][8]; };
static constexpr BandTabs mk_tabs() {
    constexpr float GW[11] = {
        0.00102838f, 0.00759876f, 0.03600026f, 0.10936083f, 0.21300567f,
        0.26601190f, 0.21300567f, 0.10936083f, 0.03600026f, 0.00759876f,
        0.00102838f};
    BandTabs t{};
    for (int lane = 0; lane < 64; ++lane) {
        const int l15 = lane & 15, kg = lane >> 4;
        for (int j = 0; j < 8; ++j) {
            const int kk = kg * 8 + j;
            const int ib = kk - l15 - 3;
            const int iv = kk - l15;
            t.bh[lane][j] = (ib >= 0 && ib < 11) ? GW[ib] : 0.0f;
            t.wv[lane][j] = (iv >= 0 && iv < 11) ? GW[iv] : 0.0f;
        }
    }
    return t;
}
__device__ constexpr BandTabs TAB = mk_tabs();

static __device__ __forceinline__ f16x8 load_band(const float* row) {
    const float4 a = *(const float4*)row;
    const float4 b = *(const float4*)(row + 4);
    U8 r;
    r.p[0] = pkrtz(a.x, a.y); r.p[1] = pkrtz(a.z, a.w);
    r.p[2] = pkrtz(b.x, b.y); r.p[3] = pkrtz(b.z, b.w);
    return r.v;
}

__global__ __launch_bounds__(256, 8) void ssim_main(
    const float* __restrict__ X, const float* __restrict__ Y,
    float* __restrict__ partial)
{
    __shared__ _Float16 rawx[48 * RAWP];   // 8,448 B
    __shared__ _Float16 rawy[48 * RAWP];   // 8,448 B
    __shared__ float red[4];

    const int tid = threadIdx.x;
    const int bid = blockIdx.x;

    // bijective XCD swizzle
    const int wg    = (bid & 7) * (NBLOCKS / 8) + (bid >> 3);
    const int plane = wg >> 7;           // 128 tiles per plane
    const int tt    = wg & 127;
    const int tr    = tt >> 3;           // 0..15 (row tiles, 32 rows)
    const int tc    = tt & 7;            // 0..7  (col tiles, 64 cols)

    const float* xp = X + (size_t)plane * (512 * 512);
    const float* yp = Y + (size_t)plane * (512 * 512);
    const int row0 = tr * 32 - 5;        // global row of raw row 0
    const int colT = tc * 64;            // global col of output col 0
    const int colB = colT - 8;           // global col of raw col 0

    // ---- coalesced staging: 48 rows x 20 float4-quads, f32 -> f16 ----
    for (int u = tid; u < 960; u += 256) {
        const int r  = u / 20;
        const int c4 = u - r * 20;
        const int gr = row0 + r;
        const int gc = colB + 4 * c4;
        const bool ok = ((unsigned)gr < 512u) && ((unsigned)gc <= 508u);
        float4 xv = make_float4(0.f, 0.f, 0.f, 0.f), yv = xv;
        if (ok) {
            xv = *(const float4*)(xp + gr * 512 + gc);
            yv = *(const float4*)(yp + gr * 512 + gc);
        }
        U4 tx, ty;
        tx.p[0] = pkrtz(xv.x, xv.y); tx.p[1] = pkrtz(xv.z, xv.w);
        ty.p[0] = pkrtz(yv.x, yv.y); ty.p[1] = pkrtz(yv.z, yv.w);
        *(f16x4*)(rawx + r * RAWP + 4 * c4) = tx.v;
        *(f16x4*)(rawy + r * RAWP + 4 * c4) = ty.v;
    }

    const int w    = tid >> 6;           // wave id = n-tile (out cols 16w..)
    const int lane = tid & 63;
    const int l15  = lane & 15;
    const int kg   = lane >> 4;

    // band fragments from constant tables (overlaps staging latency)
    const f16x8 BH = load_band(TAB.bh[lane]);
    const f16x8 WV = load_band(TAB.wv[lane]);

    __syncthreads();                     // raw panels ready

    const f32x4 zero4 = {0.f, 0.f, 0.f, 0.f};
    const int rawc = 16 * w + 8 * kg;    // phase-A raw col (8 f16, 16B aligned)

    // ---- Phase A: fragments, products, h-blur MFMA -> packed C in regs ----
    // pq[q][mt][half]: half0 = rows(4kg,4kg+1), half1 = rows(4kg+2,4kg+3)
    unsigned pq[4][3][2];
#pragma unroll
    for (int mt = 0; mt < 3; ++mt) {
        const int r = mt * 16 + l15;
        const f16x8 fx = *(const f16x8*)(rawx + r * RAWP + rawc);
        const f16x8 fy = *(const f16x8*)(rawy + r * RAWP + rawc);
        const f16x8 fxy = fx * fy;
        const f16x8 fss = fx * fx + fy * fy;

        const f32x4 c0 = __builtin_amdgcn_mfma_f32_16x16x32_f16(fx,  BH, zero4, 0, 0, 0);
        const f32x4 c1 = __builtin_amdgcn_mfma_f32_16x16x32_f16(fy,  BH, zero4, 0, 0, 0);
        const f32x4 c2 = __builtin_amdgcn_mfma_f32_16x16x32_f16(fss, BH, zero4, 0, 0, 0);
        const f32x4 c3 = __builtin_amdgcn_mfma_f32_16x16x32_f16(fxy, BH, zero4, 0, 0, 0);

        pq[0][mt][0] = pk_u32(c0[0], c0[1]); pq[0][mt][1] = pk_u32(c0[2], c0[3]);
        pq[1][mt][0] = pk_u32(c1[0], c1[1]); pq[1][mt][1] = pk_u32(c1[2], c1[3]);
        pq[2][mt][0] = pk_u32(c2[0], c2[1]); pq[2][mt][1] = pk_u32(c2[2], c2[3]);
        pq[3][mt][0] = pk_u32(c3[0], c3[1]); pq[3][mt][1] = pk_u32(c3[2], c3[3]);
    }

    // ---- Phase C: bpermute-built B-frags, v-blur MFMA, epilogue ----
    const int addrA = ((2 * (kg & 1)) * 16 + l15) * 4;   // byte lane addr
    const int addrB = addrA + 64;                        // +16 lanes
    const bool hi = (kg >= 2);                           // mt-set = mtv+1

    const float C1 = 0.0004f, C2 = 0.0036f;
    float lsum = 0.f;
#pragma unroll
    for (int mtv = 0; mtv < 2; ++mtv) {
        f32x4 v[4];
#pragma unroll
        for (int q = 0; q < 4; ++q) {
            const unsigned s0 = hi ? pq[q][mtv + 1][0] : pq[q][mtv][0];
            const unsigned s1 = hi ? pq[q][mtv + 1][1] : pq[q][mtv][1];
            UB b;
            b.u[0] = (unsigned)__builtin_amdgcn_ds_bpermute(addrA, (int)s0);
            b.u[1] = (unsigned)__builtin_amdgcn_ds_bpermute(addrA, (int)s1);
            b.u[2] = (unsigned)__builtin_amdgcn_ds_bpermute(addrB, (int)s0);
            b.u[3] = (unsigned)__builtin_amdgcn_ds_bpermute(addrB, (int)s1);
            v[q] = __builtin_amdgcn_mfma_f32_16x16x32_f16(WV, b.v, zero4, 0, 0, 0);
        }
#pragma unroll
        for (int r2 = 0; r2 < 4; ++r2) {
            const float mux = v[0][r2], muy = v[1][r2];
            const float ess = v[2][r2], exy = v[3][r2];
            const float mux2 = mux * mux, muy2 = muy * muy, muxy = mux * muy;
            const float svar = fmaxf(ess - mux2 - muy2, 0.f);  // sxx+syy
            const float sxy = exy - muxy;
            const float num = (2.f * muxy + C1) * (2.f * sxy + C2);
            const float den = (mux2 + muy2 + C1) * (svar + C2);
            lsum += num * __builtin_amdgcn_rcpf(den);
        }
    }

    // ---- block reduction ----
#pragma unroll
    for (int off = 32; off > 0; off >>= 1)
        lsum += __shfl_down(lsum, off, 64);
    if (lane == 0) red[w] = lsum;
    __syncthreads();
    if (tid == 0)
        partial[bid] = red[0] + red[1] + red[2] + red[3];
}

__global__ void ssim_final(const float* __restrict__ partial,
                           float* __restrict__ out)
{
    const int tid = threadIdx.x;
    double s = 0.0;
    for (int i = tid; i < NBLOCKS; i += 1024) s += (double)partial[i];
#pragma unroll
    for (int off = 32; off > 0; off >>= 1)
        s += __shfl_down(s, off, 64);
    __shared__ double ws[16];
    if ((tid & 63) == 0) ws[tid >> 6] = s;
    __syncthreads();
    if (tid == 0) {
        double tot = 0.0;
#pragma unroll
        for (int i = 0; i < 16; ++i) tot += ws[i];
        out[0] = (float)(1.0 - tot / (double)NPIX);
    }
}

extern "C" void kernel_launch(void* const* d_in, const int* in_sizes, int n_in,
                              void* d_out, int out_size, void* d_ws, size_t ws_size,
                              hipStream_t stream)
{
    const float* x = (const float*)d_in[0];   // pred
    const float* y = (const float*)d_in[1];   // target
    float* partial = (float*)d_ws;            // NBLOCKS*4 = 24,576 B
    float* out = (float*)d_out;

    ssim_main<<<NBLOCKS, 256, 0, stream>>>(x, y, partial);
    ssim_final<<<1, 1024, 0, stream>>>(partial, out);
}